// Round 9
// baseline (73.610 us; speedup 1.0000x reference)
//
#include <hip/hip_runtime.h>

// Two-dispatch design:
//   dispatch 1: hm_loss_kernel   (4096 blocks) — also zeroes the completion ctr
//   dispatch 2: reg_finalize_kernel (64 blocks) — gather loss; last-done block
//               reduces ALL partials (hm's are complete: same-stream ordering)
//               and writes the 4 outputs.
// ws layout (floats):
//   [0 .. 3*NB_HM)                 hm partials per block:  {loss_sum, num_pos, cnt}
//   [REG_OFF .. REG_OFF+3*NB_REG)  reg partials per block: {wh_sum, off_sum, mask_sum}
//   [CTR_IDX]                      int completion counter (zeroed by hm kernel)
#define NB_HM   4096
#define NB_REG  64
#define REG_OFF (3 * NB_HM)
#define CTR_IDX (REG_OFF + 3 * NB_REG)   // 12480

typedef float f32x4 __attribute__((ext_vector_type(4)));

__device__ __forceinline__ float wave_sum(float v) {
    #pragma unroll
    for (int off = 32; off > 0; off >>= 1) v += __shfl_down(v, off, 64);
    return v;
}

__device__ __forceinline__ void block_reduce_store3(float a, float b, float c,
                                                    float* __restrict__ dst) {
    a = wave_sum(a); b = wave_sum(b); c = wave_sum(c);
    __shared__ float sa[4], sb[4], sc[4];
    int lane = threadIdx.x & 63;
    int wave = threadIdx.x >> 6;
    if (lane == 0) { sa[wave] = a; sb[wave] = b; sc[wave] = c; }
    __syncthreads();
    if (threadIdx.x == 0) {
        float ta = 0.f, tb = 0.f, tc = 0.f;
        #pragma unroll
        for (int w = 0; w < 4; ++w) { ta += sa[w]; tb += sb[w]; tc += sc[w]; }
        dst[0] = ta; dst[1] = tb; dst[2] = tc;
    }
}

// Focal-loss element (validated R3/R4/R6/R8).
__device__ __forceinline__ void hm_elem(float x, float gt, float& s_loss,
                                        unsigned& posc, unsigned& cntc) {
    bool pos = (gt == 1.0f);
    float e = __expf(-x);
    float p = __builtin_amdgcn_rcpf(1.0f + e);
    p = fminf(fmaxf(p, 1e-4f), 1.0f - 1e-4f);
    float arg = pos ? p : 1.0f - p;
    float a   = 1.0f - arg;
    float b   = pos ? 1.0f : 1.0f - gt;
    float b2  = b * b;
    float l   = __logf(arg);
    s_loss += (a * a) * (b2 * b2) * l;
    posc += (unsigned)__popcll(__ballot(pos));
    cntc += (unsigned)__popcll(__ballot(p > 0.3f));
}

#define COMPV(P, G)                                    \
    do {                                               \
        hm_elem((P)[0], (G)[0], s_loss, posc, cntc);   \
        hm_elem((P)[1], (G)[1], s_loss, posc, cntc);   \
        hm_elem((P)[2], (G)[2], s_loss, posc, cntc);   \
        hm_elem((P)[3], (G)[3], s_loss, posc, cntc);   \
    } while (0)

__global__ void __launch_bounds__(256)
hm_loss_kernel(const f32x4* __restrict__ p4,
               const f32x4* __restrict__ g4,
               float* __restrict__ ws, long long N4) {
    // Zero the completion counter for the follow-up kernel. Visible device-wide
    // at this dispatch's end (same-stream ordering + end-of-kernel flush).
    if (blockIdx.x == 0 && threadIdx.x == 0)
        *(volatile int*)&ws[CTR_IDX] = 0;

    float    s_loss = 0.f;
    unsigned posc = 0, cntc = 0;

    // Contiguous-segment partition (R8 win): block b owns one linear slice,
    // marching 4 KB/iteration. 4096 blocks -> 40 KB slices, 2 scheduling
    // rounds, finer-grained XCD self-balancing than 2048.
    if ((N4 % ((long long)NB_HM * 256)) == 0) {
        long long per_block = N4 / NB_HM;               // float4s per block
        long long nIter     = per_block >> 8;           // / 256 threads
        long long i = (long long)blockIdx.x * per_block + threadIdx.x;

        long long j = 0;
        for (; j + 3 < nIter; j += 4, i += 1024) {
            f32x4 xp0 = p4[i];
            f32x4 xp1 = p4[i + 256];
            f32x4 xp2 = p4[i + 512];
            f32x4 xp3 = p4[i + 768];
            f32x4 xg0 = g4[i];
            f32x4 xg1 = g4[i + 256];
            f32x4 xg2 = g4[i + 512];
            f32x4 xg3 = g4[i + 768];
            COMPV(xp0, xg0);
            COMPV(xp1, xg1);
            COMPV(xp2, xg2);
            COMPV(xp3, xg3);
        }
        for (; j < nIter; ++j, i += 256) {
            f32x4 xp = p4[i];
            f32x4 xg = g4[i];
            COMPV(xp, xg);
        }
    } else {
        long long tid = (long long)blockIdx.x * blockDim.x + threadIdx.x;
        long long NT  = (long long)gridDim.x * blockDim.x;
        for (long long i = tid; i < N4; i += NT) {
            f32x4 xp = p4[i];
            f32x4 xg = g4[i];
            COMPV(xp, xg);
        }
    }

    int lane = threadIdx.x & 63;
    float fpos = (lane == 0) ? (float)posc : 0.f;
    float fcnt = (lane == 0) ? (float)cntc : 0.f;
    block_reduce_store3(s_loss, fpos, fcnt, &ws[3 * (size_t)blockIdx.x]);
}

__device__ __forceinline__ float smooth_l1(float d) {
    float ad = fabsf(d);
    return (ad < 1.0f) ? 0.5f * d * d : ad - 0.5f;
}

__global__ void __launch_bounds__(256)
reg_finalize_kernel(const float* __restrict__ wh_pred,  const float* __restrict__ wh_gt,
                    const float* __restrict__ off_pred, const float* __restrict__ off_gt,
                    const int* __restrict__ mask, const int* __restrict__ ind,
                    float* __restrict__ ws, float* __restrict__ out,
                    int BK, int K, int HW) {
    // ---- wh/off smooth-L1 gather partials ----
    int t  = blockIdx.x * 256 + threadIdx.x;
    int nt = NB_REG * 256;
    float s_wh = 0.f, s_off = 0.f, s_m = 0.f;

    for (int i = t; i < BK; i += nt) {
        int b   = i / K;
        float m = (float)mask[i];
        int idx = ind[i];
        const float* wb = wh_pred  + (size_t)b * 2 * HW;
        const float* ob = off_pred + (size_t)b * 2 * HW;
        #pragma unroll
        for (int c = 0; c < 2; ++c) {
            float gw = wb[(size_t)c * HW + idx];
            float tw = wh_gt[(size_t)i * 2 + c];
            s_wh += smooth_l1(gw * m - tw * m);

            float go = ob[(size_t)c * HW + idx];
            float to = off_gt[(size_t)i * 2 + c];
            s_off += smooth_l1(go * m - to * m);
        }
        s_m += 2.0f * m;
    }

    block_reduce_store3(s_wh, s_off, s_m, &ws[REG_OFF + 3 * (size_t)blockIdx.x]);

    // ---- last-done block reduces everything (hm partials already complete:
    //      hm kernel finished before this dispatch started) ----
    __shared__ int s_last;
    if (threadIdx.x == 0) {
        __threadfence();                         // release this block's partial
        int old = atomicAdd((int*)&ws[CTR_IDX], 1);
        s_last = (old == NB_REG - 1) ? 1 : 0;
    }
    __syncthreads();
    if (!s_last) return;
    __threadfence();                             // acquire all reg partials

    float a = 0.f, b = 0.f, c = 0.f, w = 0.f, o = 0.f, m = 0.f;
    for (int i = threadIdx.x; i < NB_HM; i += 256) {
        a += ws[3 * i + 0];
        b += ws[3 * i + 1];
        c += ws[3 * i + 2];
    }
    if (threadIdx.x < 3 * NB_REG) {              // 192 threads, one float each
        float v = ws[REG_OFF + threadIdx.x];
        int r = threadIdx.x % 3;
        w = (r == 0) ? v : 0.f;
        o = (r == 1) ? v : 0.f;
        m = (r == 2) ? v : 0.f;
    }

    a = wave_sum(a); b = wave_sum(b); c = wave_sum(c);
    w = wave_sum(w); o = wave_sum(o); m = wave_sum(m);

    __shared__ float s[6][4];
    int lane = threadIdx.x & 63, wv = threadIdx.x >> 6;
    if (lane == 0) {
        s[0][wv] = a; s[1][wv] = b; s[2][wv] = c;
        s[3][wv] = w; s[4][wv] = o; s[5][wv] = m;
    }
    __syncthreads();
    if (threadIdx.x == 0) {
        float tt[6];
        #pragma unroll
        for (int k = 0; k < 6; ++k)
            tt[k] = s[k][0] + s[k][1] + s[k][2] + s[k][3];

        float loss_sum = -tt[0];
        float num_pos  = tt[1];
        float fallback = fmaxf(tt[2], 1.0f);
        float denom    = (num_pos == 0.0f) ? fallback : num_pos;
        float hm_loss  = loss_sum / denom;
        float md       = tt[5] + 1e-4f;
        float wh_loss  = tt[3] / md;
        float off_loss = tt[4] / md;
        out[0] = hm_loss;
        out[1] = wh_loss;
        out[2] = off_loss;
        out[3] = hm_loss + 0.1f * wh_loss + off_loss;
    }
}

extern "C" void kernel_launch(void* const* d_in, const int* in_sizes, int n_in,
                              void* d_out, int out_size, void* d_ws, size_t ws_size,
                              hipStream_t stream) {
    const float* hm_pred  = (const float*)d_in[0];
    const float* hm_gt    = (const float*)d_in[1];
    const float* wh_pred  = (const float*)d_in[2];
    const float* wh_gt    = (const float*)d_in[3];
    const float* off_pred = (const float*)d_in[4];
    const float* off_gt   = (const float*)d_in[5];
    const int*   mask     = (const int*)d_in[6];
    const int*   ind      = (const int*)d_in[7];
    float*       out      = (float*)d_out;
    float*       ws       = (float*)d_ws;

    long long N  = in_sizes[0];          // B*C*H*W
    int       BK = in_sizes[6];          // B*K
    const int K  = 128;                  // per reference setup
    int       B  = BK / K;
    int       HW = in_sizes[2] / (2 * B);

    hm_loss_kernel<<<NB_HM, 256, 0, stream>>>((const f32x4*)hm_pred,
                                              (const f32x4*)hm_gt, ws, N >> 2);
    reg_finalize_kernel<<<NB_REG, 256, 0, stream>>>(wh_pred, wh_gt, off_pred, off_gt,
                                                    mask, ind, ws, out, BK, K, HW);
}

// Round 10
// 71.450 us; speedup vs baseline: 1.0302x; 1.0302x over previous
//
#include <hip/hip_runtime.h>

// FINAL (R8 configuration — best measured: 72.8 µs).
// ws layout (floats), all written unconditionally every launch (no memset needed):
//   [0 .. 3*NB_HM)                 hm partials per block:  {loss_sum, num_pos, cnt}
//   [REG_OFF .. REG_OFF+3*NB_REG)  reg partials per block: {wh_sum, off_sum, mask_sum}
#define NB_HM   2048
#define NB_REG  64
#define REG_OFF (3 * NB_HM)

typedef float f32x4 __attribute__((ext_vector_type(4)));

__device__ __forceinline__ float wave_sum(float v) {
    #pragma unroll
    for (int off = 32; off > 0; off >>= 1) v += __shfl_down(v, off, 64);
    return v;
}

__device__ __forceinline__ void block_reduce_store3(float a, float b, float c,
                                                    float* __restrict__ dst) {
    a = wave_sum(a); b = wave_sum(b); c = wave_sum(c);
    __shared__ float sa[8], sb[8], sc[8];
    int lane = threadIdx.x & 63;
    int wave = threadIdx.x >> 6;
    if (lane == 0) { sa[wave] = a; sb[wave] = b; sc[wave] = c; }
    __syncthreads();
    if (threadIdx.x == 0) {
        int nw = blockDim.x >> 6;
        float ta = 0.f, tb = 0.f, tc = 0.f;
        for (int w = 0; w < nw; ++w) { ta += sa[w]; tb += sb[w]; tc += sc[w]; }
        dst[0] = ta; dst[1] = tb; dst[2] = tc;
    }
}

// Focal-loss element. pos: (1-p)^2 log(p); neg: p^2 (1-gt)^4 log(1-p).
// Counters ride the scalar pipe via ballot/popc.
__device__ __forceinline__ void hm_elem(float x, float gt, float& s_loss,
                                        unsigned& posc, unsigned& cntc) {
    bool pos = (gt == 1.0f);
    float e = __expf(-x);
    float p = __builtin_amdgcn_rcpf(1.0f + e);
    p = fminf(fmaxf(p, 1e-4f), 1.0f - 1e-4f);
    float arg = pos ? p : 1.0f - p;
    float a   = 1.0f - arg;
    float b   = pos ? 1.0f : 1.0f - gt;
    float b2  = b * b;
    float l   = __logf(arg);
    s_loss += (a * a) * (b2 * b2) * l;
    posc += (unsigned)__popcll(__ballot(pos));
    cntc += (unsigned)__popcll(__ballot(p > 0.3f));
}

#define COMPV(P, G)                                    \
    do {                                               \
        hm_elem((P)[0], (G)[0], s_loss, posc, cntc);   \
        hm_elem((P)[1], (G)[1], s_loss, posc, cntc);   \
        hm_elem((P)[2], (G)[2], s_loss, posc, cntc);   \
        hm_elem((P)[3], (G)[3], s_loss, posc, cntc);   \
    } while (0)

__global__ void __launch_bounds__(256)
hm_loss_kernel(const f32x4* __restrict__ p4,
               const f32x4* __restrict__ g4,
               float* __restrict__ ws, long long N4) {
    float    s_loss = 0.f;
    unsigned posc = 0, cntc = 0;

    // Contiguous-segment partition (R8 win, -5%): block b owns one 80 KB
    // linear slice, marching 4 KB/iteration — DRAM row locality + de-lockstep
    // vs the 8 MB-jump grid-stride walk (R1-R6, stuck at ~4.8 TB/s).
    if ((N4 % ((long long)NB_HM * 256)) == 0) {
        long long per_block = N4 / NB_HM;               // float4s per block
        long long nIter     = per_block >> 8;           // / 256 threads
        long long i = (long long)blockIdx.x * per_block + threadIdx.x;

        long long j = 0;
        for (; j + 3 < nIter; j += 4, i += 1024) {
            f32x4 xp0 = p4[i];
            f32x4 xp1 = p4[i + 256];
            f32x4 xp2 = p4[i + 512];
            f32x4 xp3 = p4[i + 768];
            f32x4 xg0 = g4[i];
            f32x4 xg1 = g4[i + 256];
            f32x4 xg2 = g4[i + 512];
            f32x4 xg3 = g4[i + 768];
            COMPV(xp0, xg0);
            COMPV(xp1, xg1);
            COMPV(xp2, xg2);
            COMPV(xp3, xg3);
        }
        for (; j < nIter; ++j, i += 256) {
            f32x4 xp = p4[i];
            f32x4 xg = g4[i];
            COMPV(xp, xg);
        }
    } else {
        long long tid = (long long)blockIdx.x * blockDim.x + threadIdx.x;
        long long NT  = (long long)gridDim.x * blockDim.x;
        for (long long i = tid; i < N4; i += NT) {
            f32x4 xp = p4[i];
            f32x4 xg = g4[i];
            COMPV(xp, xg);
        }
    }

    int lane = threadIdx.x & 63;
    float fpos = (lane == 0) ? (float)posc : 0.f;
    float fcnt = (lane == 0) ? (float)cntc : 0.f;
    block_reduce_store3(s_loss, fpos, fcnt, &ws[3 * (size_t)blockIdx.x]);
}

__device__ __forceinline__ float smooth_l1(float d) {
    float ad = fabsf(d);
    return (ad < 1.0f) ? 0.5f * d * d : ad - 0.5f;
}

__global__ void __launch_bounds__(256)
reg_loss_kernel(const float* __restrict__ wh_pred,  const float* __restrict__ wh_gt,
                const float* __restrict__ off_pred, const float* __restrict__ off_gt,
                const int* __restrict__ mask, const int* __restrict__ ind,
                float* __restrict__ ws, int BK, int K, int HW) {
    int t = blockIdx.x * blockDim.x + threadIdx.x;
    int nt = gridDim.x * blockDim.x;
    float s_wh = 0.f, s_off = 0.f, s_m = 0.f;

    for (int i = t; i < BK; i += nt) {
        int b   = i / K;
        float m = (float)mask[i];
        int idx = ind[i];
        const float* wb = wh_pred  + (size_t)b * 2 * HW;
        const float* ob = off_pred + (size_t)b * 2 * HW;
        #pragma unroll
        for (int c = 0; c < 2; ++c) {
            float gw = wb[(size_t)c * HW + idx];
            float tw = wh_gt[(size_t)i * 2 + c];
            s_wh += smooth_l1(gw * m - tw * m);

            float go = ob[(size_t)c * HW + idx];
            float to = off_gt[(size_t)i * 2 + c];
            s_off += smooth_l1(go * m - to * m);
        }
        s_m += 2.0f * m;
    }

    block_reduce_store3(s_wh, s_off, s_m, &ws[REG_OFF + 3 * (size_t)blockIdx.x]);
}

__global__ void __launch_bounds__(1024)
reduce_finalize_kernel(const float* __restrict__ ws, float* __restrict__ out) {
    float a = 0.f, b = 0.f, c = 0.f, w = 0.f, o = 0.f, m = 0.f;
    for (int i = threadIdx.x; i < NB_HM; i += 1024) {
        a += ws[3 * i + 0];
        b += ws[3 * i + 1];
        c += ws[3 * i + 2];
    }
    if (threadIdx.x < 3 * NB_REG) {
        float v = ws[REG_OFF + threadIdx.x];
        int r = threadIdx.x % 3;
        w = (r == 0) ? v : 0.f;
        o = (r == 1) ? v : 0.f;
        m = (r == 2) ? v : 0.f;
    }

    a = wave_sum(a); b = wave_sum(b); c = wave_sum(c);
    w = wave_sum(w); o = wave_sum(o); m = wave_sum(m);

    __shared__ float s[6][16];
    int lane = threadIdx.x & 63, wv = threadIdx.x >> 6;
    if (lane == 0) {
        s[0][wv] = a; s[1][wv] = b; s[2][wv] = c;
        s[3][wv] = w; s[4][wv] = o; s[5][wv] = m;
    }
    __syncthreads();
    if (threadIdx.x == 0) {
        float t[6];
        #pragma unroll
        for (int k = 0; k < 6; ++k) {
            float acc = 0.f;
            for (int q = 0; q < 16; ++q) acc += s[k][q];
            t[k] = acc;
        }
        float loss_sum = -t[0];
        float num_pos  = t[1];
        float fallback = fmaxf(t[2], 1.0f);
        float denom    = (num_pos == 0.0f) ? fallback : num_pos;
        float hm_loss  = loss_sum / denom;
        float md       = t[5] + 1e-4f;
        float wh_loss  = t[3] / md;
        float off_loss = t[4] / md;
        out[0] = hm_loss;
        out[1] = wh_loss;
        out[2] = off_loss;
        out[3] = hm_loss + 0.1f * wh_loss + off_loss;
    }
}

extern "C" void kernel_launch(void* const* d_in, const int* in_sizes, int n_in,
                              void* d_out, int out_size, void* d_ws, size_t ws_size,
                              hipStream_t stream) {
    const float* hm_pred  = (const float*)d_in[0];
    const float* hm_gt    = (const float*)d_in[1];
    const float* wh_pred  = (const float*)d_in[2];
    const float* wh_gt    = (const float*)d_in[3];
    const float* off_pred = (const float*)d_in[4];
    const float* off_gt   = (const float*)d_in[5];
    const int*   mask     = (const int*)d_in[6];
    const int*   ind      = (const int*)d_in[7];
    float*       out      = (float*)d_out;
    float*       ws       = (float*)d_ws;

    long long N  = in_sizes[0];          // B*C*H*W
    int       BK = in_sizes[6];          // B*K
    const int K  = 128;                  // per reference setup
    int       B  = BK / K;
    int       HW = in_sizes[2] / (2 * B);

    hm_loss_kernel<<<NB_HM, 256, 0, stream>>>((const f32x4*)hm_pred,
                                              (const f32x4*)hm_gt, ws, N >> 2);
    reg_loss_kernel<<<NB_REG, 256, 0, stream>>>(wh_pred, wh_gt, off_pred, off_gt,
                                                mask, ind, ws, BK, K, HW);
    reduce_finalize_kernel<<<1, 1024, 0, stream>>>(ws, out);
}